// Round 8
// baseline (1092.592 us; speedup 1.0000x reference)
//
#include <hip/hip_runtime.h>
#include <math.h>

// Problem constants
#define LL 4096
#define BATCH 32
#define NIC 128
#define NFC 128

typedef __attribute__((ext_vector_type(8))) short short8;
typedef __attribute__((ext_vector_type(4))) float floatx4;

__device__ __forceinline__ unsigned short f2bf(float f) {
  unsigned u = __builtin_bit_cast(unsigned, f);
  u += 0x7fffu + ((u >> 16) & 1u);  // round-to-nearest-even
  return (unsigned short)(u >> 16);
}
__device__ __forceinline__ float bf2f(unsigned short h) {
  unsigned u = ((unsigned)h) << 16;
  return __builtin_bit_cast(float, u);
}

// ---------------------------------------------------------------------------
// Weight prep: src fp32 [O=128][I=128][K] -> dst bf16 [k][cig(16)][o(128)][8]
// where ci = cig*8 + e.  MFMA A-fragment load for (o, kc, lhi) is then
// 16 llo-lanes x 16 B CONTIGUOUS (256-B segments) -> coalesced L2 reads.
// ---------------------------------------------------------------------------
__global__ void wtransb(const float* __restrict__ src,
                        unsigned short* __restrict__ dst, int K, int n) {
  int f = blockIdx.x * 256 + threadIdx.x;
  if (f >= n) return;
  int o   = f / (128 * K);
  int rem = f - o * 128 * K;
  int ci  = rem / K;
  int k   = rem - ci * K;
  dst[((k * 16 + (ci >> 3)) * 128 + o) * 8 + (ci & 7)] = f2bf(src[f]);
}

// ---------------------------------------------------------------------------
// Prepass: x fp32 [b][ci][l] -> Xt bf16 [b][l][ci]  (LDS tile transpose)
// ---------------------------------------------------------------------------
__launch_bounds__(256)
__global__ void prep_xt(const float* __restrict__ x,
                        unsigned short* __restrict__ xt) {
  __shared__ unsigned short tb[64 * 136];
  const int b  = blockIdx.y;
  const int l0 = blockIdx.x * 64;
  const int t  = threadIdx.x;
  for (int idx = t; idx < 2048; idx += 256) {
    int ci = idx >> 4;
    int l4 = (idx & 15) * 4;
    float4 v = *(const float4*)&x[((size_t)b * 128 + ci) * LL + l0 + l4];
    tb[(l4 + 0) * 136 + ci] = f2bf(v.x);
    tb[(l4 + 1) * 136 + ci] = f2bf(v.y);
    tb[(l4 + 2) * 136 + ci] = f2bf(v.z);
    tb[(l4 + 3) * 136 + ci] = f2bf(v.w);
  }
  __syncthreads();
  for (int idx = t; idx < 1024; idx += 256) {
    int l  = idx >> 4;
    int cg = (idx & 15) * 8;
    *(short8*)&xt[((size_t)b * LL + l0 + l) * 128 + cg] =
        *(const short8*)&tb[l * 136 + cg];
  }
}

// ---------------------------------------------------------------------------
// FUSED conv branches via bf16 MFMA — role-split for occupancy.
// Ft output now K-MAJOR: Ft2[b][kg=(br*128+o)>>3][l][8] so the bottleneck
// GEMM's B-fragment loads are 256-B-contiguous direct-from-L2 (no LDS).
// ---------------------------------------------------------------------------
__launch_bounds__(256)
__global__ void conv_all(const unsigned short* __restrict__ xt,
                         const unsigned short* __restrict__ wtb,
                         unsigned short* __restrict__ Ft,
                         float* __restrict__ gsum) {
  __shared__ unsigned short Bs[82 * 136];
  const int role = blockIdx.z;
  const int halo = role ? 4 : 9;
  const int rows = role ? 72 : 82;
  const int b  = blockIdx.y;
  const int l0 = blockIdx.x * 64;
  const int t  = threadIdx.x;
  const int lane = t & 63;
  const int wo   = t >> 6;  // wave id = o-group (32 o each)
  const int lhi = lane >> 4;
  const int llo = lane & 15;
  const unsigned short* xb = xt + (size_t)b * LL * 128;

  // ---- stage x tile once (bf16), halo zero-padded ----
  for (int idx = t; idx < rows * 16; idx += 256) {
    int r  = idx >> 4;
    int cg = (idx & 15) * 8;
    int l  = l0 - halo + r;
    short8 v = {0, 0, 0, 0, 0, 0, 0, 0};
    if (l >= 0 && l < LL) v = *(const short8*)&xb[(size_t)l * 128 + cg];
    *(short8*)&Bs[r * 136 + cg] = v;
  }
  __syncthreads();

  const int brlo = role ? 1 : 0;
  const int brhi = role ? 5 : 1;
#pragma clang loop unroll(disable)
  for (int br = brlo; br < brhi; ++br) {
    if (br == 4) {
      // ---- in-LDS maxpool3 of central 64 rows (rows halo..halo+63) ----
      short8 pv[4];
#pragma unroll
      for (int i = 0; i < 4; ++i) {
        int idx = t + i * 256;
        int r  = idx >> 4;
        int cg = (idx & 15) * 8;
        int l  = l0 + r;
        float m[8];
#pragma unroll
        for (int e = 0; e < 8; ++e) m[e] = -INFINITY;
#pragma unroll
        for (int d = 0; d < 3; ++d) {
          int ls = l - 1 + d;
          if (ls >= 0 && ls < LL) {
            short8 v = *(const short8*)&Bs[(r + halo - 1 + d) * 136 + cg];
#pragma unroll
            for (int e = 0; e < 8; ++e)
              m[e] = fmaxf(m[e], bf2f((unsigned short)v[e]));
          }
        }
#pragma unroll
        for (int e = 0; e < 8; ++e) pv[i][e] = (short)f2bf(m[e]);
      }
      __syncthreads();
#pragma unroll
      for (int i = 0; i < 4; ++i) {
        int idx = t + i * 256;
        int r  = idx >> 4;
        int cg = (idx & 15) * 8;
        *(short8*)&Bs[(r + halo) * 136 + cg] = pv[i];
      }
      __syncthreads();
    }

    int K, wof;
    switch (br) {
      case 0:  K = 19; wof = 0;      break;
      case 1:  K = 9;  wof = 311296; break;
      case 2:  K = 5;  wof = 458752; break;
      case 3:  K = 1;  wof = 540672; break;
      default: K = 1;  wof = 557056; break;
    }
    const int roff = halo - K / 2;

    floatx4 acc[2][4];
#pragma unroll
    for (int oi = 0; oi < 2; ++oi)
#pragma unroll
      for (int ni = 0; ni < 4; ++ni) acc[oi][ni] = (floatx4)0.0f;

    for (int tap = 0; tap < K; ++tap) {
      const unsigned short* wb = wtb + wof + tap * 16384;
#pragma unroll
      for (int kc = 0; kc < 4; ++kc) {
        short8 af[2], bfr[4];
#pragma unroll
        for (int oi = 0; oi < 2; ++oi) {
          int o = wo * 32 + oi * 16 + llo;
          af[oi] = *(const short8*)&wb[((kc * 4 + lhi) * 128 + o) * 8];
        }
#pragma unroll
        for (int ni = 0; ni < 4; ++ni) {
          int row = ni * 16 + llo + tap + roff;
          bfr[ni] = *(const short8*)&Bs[row * 136 + kc * 32 + lhi * 8];
        }
#pragma unroll
        for (int oi = 0; oi < 2; ++oi)
#pragma unroll
          for (int ni = 0; ni < 4; ++ni)
            acc[oi][ni] = __builtin_amdgcn_mfma_f32_16x16x32_bf16(
                af[oi], bfr[ni], acc[oi][ni], 0, 0, 0);
      }
    }

    // ---- epilogue: Ft2 k-major (jo = br*128+wo*32+oi*16+lhi*4+r) ----
#pragma unroll
    for (int oi = 0; oi < 2; ++oi) {
#pragma unroll
      for (int ni = 0; ni < 4; ++ni) {
        int kg = br * 16 + wo * 4 + oi * 2 + (lhi >> 1);
        int so = (lhi & 1) * 4;
        int l  = l0 + ni * 16 + llo;
        unsigned short tmp[4];
#pragma unroll
        for (int r = 0; r < 4; ++r) tmp[r] = f2bf(acc[oi][ni][r]);
        *(uint2*)&Ft[(((size_t)b * 80 + kg) * LL + l) * 8 + so] =
            *(uint2*)tmp;
      }
    }
#pragma unroll
    for (int oi = 0; oi < 2; ++oi) {
#pragma unroll
      for (int r = 0; r < 4; ++r) {
        float ps =
            acc[oi][0][r] + acc[oi][1][r] + acc[oi][2][r] + acc[oi][3][r];
        ps += __shfl_xor(ps, 1);
        ps += __shfl_xor(ps, 2);
        ps += __shfl_xor(ps, 4);
        ps += __shfl_xor(ps, 8);
        if (llo == 0)
          atomicAdd(&gsum[((size_t)br * BATCH + b) * NFC + wo * 32 + oi * 16 +
                          lhi * 4 + r],
                    ps);
      }
    }
  }
}

// ---------------------------------------------------------------------------
// Attention + SE head (unchanged)
// ---------------------------------------------------------------------------
__launch_bounds__(128)
__global__ void attn_se(const float* __restrict__ gsum,
                        const float* __restrict__ qkvw,
                        const float* __restrict__ qkvb,
                        const float* __restrict__ sew1,
                        const float* __restrict__ sew2,
                        float* __restrict__ attg, float* __restrict__ sg) {
  __shared__ float gap[640];
  __shared__ float qkvv[1920];
  __shared__ float en[100];
  __shared__ float att[25];
  __shared__ float h1[40];
  __shared__ float yv[640];
  const int b = blockIdx.x;
  const int t = threadIdx.x;

  for (int i = t; i < 640; i += 128) {
    int jj = i >> 7, c = i & 127;
    gap[i] = gsum[((size_t)jj * BATCH + b) * NFC + c] * (1.0f / 4096.0f);
  }
  __syncthreads();
  for (int rr = t; rr < 1920; rr += 128) {
    int i = rr / 384, r = rr - i * 384;
    const float* wr = qkvw + (size_t)r * 128;
    float a = qkvb[r];
    for (int c = 0; c < 128; ++c) a = fmaf(wr[c], gap[i * 128 + c], a);
    qkvv[i * 384 + r] = a;
  }
  __syncthreads();
  if (t < 100) {
    int h = t / 25, rem = t - h * 25, i = rem / 5, i2 = rem - i * 5;
    float e = 0.f;
    for (int d = 0; d < 32; ++d)
      e = fmaf(qkvv[i * 384 + h * 96 + d * 3],
               qkvv[i2 * 384 + h * 96 + d * 3 + 1], e);
    en[t] = e * 0.08838834764831845f;
  }
  __syncthreads();
  if (t < 20) {
    float* row = &en[t * 5];
    float mx = row[0];
    for (int k = 1; k < 5; ++k) mx = fmaxf(mx, row[k]);
    float ex[5];
    float sm = 0.f;
    for (int k = 0; k < 5; ++k) { ex[k] = expf(row[k] - mx); sm += ex[k]; }
    float inv = 1.0f / sm;
    for (int k = 0; k < 5; ++k) row[k] = ex[k] * inv;
  }
  __syncthreads();
  if (t < 25) {
    float a = 0.25f * (en[t] + en[25 + t] + en[50 + t] + en[75 + t]);
    att[t] = a;
    attg[b * 25 + t] = a;
  }
  __syncthreads();
  for (int i = t; i < 640; i += 128) {
    int ii = i >> 7, c = i & 127;
    float a = 0.f;
    for (int jj = 0; jj < 5; ++jj)
      a = fmaf(att[ii * 5 + jj], gap[jj * 128 + c], a);
    yv[i] = a;
  }
  __syncthreads();
  if (t < 40) {
    const float* wr = sew1 + (size_t)t * 640;
    float a = 0.f;
    for (int c = 0; c < 640; ++c) a = fmaf(wr[c], yv[c], a);
    h1[t] = fmaxf(a, 0.f);
  }
  __syncthreads();
  for (int i = t; i < 640; i += 128) {
    const float* wr = sew2 + (size_t)i * 40;
    float a = 0.f;
    for (int r = 0; r < 40; ++r) a = fmaf(wr[r], h1[r], a);
    sg[(size_t)b * 640 + i] = 1.0f / (1.0f + expf(-a));
  }
}

// ---------------------------------------------------------------------------
// Weff[b][kg][o][8] (kg=k>>3) = sum_i att[b,i,j]*s[b,k]*w_bott[o,k]  (bf16)
// ---------------------------------------------------------------------------
__launch_bounds__(256)
__global__ void make_weff(const float* __restrict__ wbott,
                          const float* __restrict__ attg,
                          const float* __restrict__ sg,
                          unsigned short* __restrict__ weff) {
  __shared__ float att[25];
  __shared__ float s[640];
  const int b = blockIdx.y;
  const int t = threadIdx.x;
  if (t < 25) att[t] = attg[b * 25 + t];
  for (int i = t; i < 640; i += 256) s[i] = sg[(size_t)b * 640 + i];
  __syncthreads();
  const int f  = blockIdx.x * 256 + t;
  const int o  = f / 640;
  const int jc = f - o * 640;
  const int jj = jc >> 7, c = jc & 127;
  float a = 0.f;
#pragma unroll
  for (int i = 0; i < 5; ++i)
    a = fmaf(att[i * 5 + jj] * s[i * 128 + c],
             wbott[(size_t)o * 640 + i * 128 + c], a);
  weff[(size_t)b * 409600 + (((size_t)(jc >> 3) * 640 + o) << 3) + (jc & 7)] =
      f2bf(a);
}

// ---------------------------------------------------------------------------
// Bottleneck GEMM v4: barrier-free, LDS-free.  Both operands kg-major:
//   A: Weff[b][kg][o][8]   B: Ft2[b][kg][l][8]
// Every fragment load is 16 lanes x 16 B contiguous (256-B L2 segments).
// No __syncthreads in the k-loop -> waves free-run, no phase-locking (the
// R6 stall: all pipes <30% busy with barrier-aligned bursts).  unroll 2
// lets the scheduler overlap next-step loads with current MFMAs.
// XCD-aware remap keeps the 5 sibling o-blocks of one Ft l-panel on one
// XCD's L2 (B reuse), bounded by launch_bounds(512,4) -> 4 waves/SIMD.
// ---------------------------------------------------------------------------
__launch_bounds__(512, 4)
__global__ void gemm_bott_mfma(const unsigned short* __restrict__ weff,
                               const unsigned short* __restrict__ ft2,
                               float* __restrict__ out,
                               float* __restrict__ bnp_s,
                               float* __restrict__ bnp_s2) {
  __shared__ float bnl_s[128];
  __shared__ float bnl_s2[128];
  const int g = blockIdx.x + 5 * (blockIdx.y + 32 * blockIdx.z);
  const int wrk = (g & 7) * 640 + (g >> 3);  // bijective: 5120 = 8 * 640
  const int ob   = wrk % 5;
  const int ybz  = wrk / 5;
  const int lblk = ybz & 31;
  const int b    = ybz >> 5;
  const int o0 = ob * 128;
  const int l0 = lblk * 128;
  const int t    = threadIdx.x;
  const int lane = t & 63;
  const int wid  = t >> 6;
  const int wo = wid & 3, wl = wid >> 2;
  const int lhi = lane >> 4;
  const int llo = lane & 15;
  const unsigned short* wb = weff + (size_t)b * 409600;
  const unsigned short* fb = ft2 + (size_t)b * 80 * LL * 8;
  if (t < 128) { bnl_s[t] = 0.f; bnl_s2[t] = 0.f; }
  __syncthreads();

  floatx4 acc[2][4];
#pragma unroll
  for (int oi = 0; oi < 2; ++oi)
#pragma unroll
    for (int ni = 0; ni < 4; ++ni) acc[oi][ni] = (floatx4)0.0f;

  const int nbase = l0 + wl * 64;

#pragma unroll 2
  for (int p = 0; p < 10; ++p) {
    short8 af[2][2], bf[2][4];
#pragma unroll
    for (int s = 0; s < 2; ++s) {
      const size_t kg = (size_t)(p * 8 + s * 4 + lhi);
#pragma unroll
      for (int oi = 0; oi < 2; ++oi) {
        int o = o0 + wo * 32 + oi * 16 + llo;
        af[s][oi] = *(const short8*)&wb[(kg * 640 + o) * 8];
      }
#pragma unroll
      for (int ni = 0; ni < 4; ++ni) {
        int n = nbase + ni * 16 + llo;
        bf[s][ni] = *(const short8*)&fb[(kg * LL + n) * 8];
      }
    }
#pragma unroll
    for (int s = 0; s < 2; ++s)
#pragma unroll
      for (int oi = 0; oi < 2; ++oi)
#pragma unroll
        for (int ni = 0; ni < 4; ++ni)
          acc[oi][ni] = __builtin_amdgcn_mfma_f32_16x16x32_bf16(
              af[s][oi], bf[s][ni], acc[oi][ni], 0, 0, 0);
  }

#pragma unroll
  for (int oi = 0; oi < 2; ++oi) {
#pragma unroll
    for (int ni = 0; ni < 4; ++ni) {
      int o = o0 + wo * 32 + oi * 16 + lhi * 4;
      int l = l0 + wl * 64 + ni * 16 + llo;
      float* op = out + ((size_t)b * 640 + o) * LL + l;
#pragma unroll
      for (int r = 0; r < 4; ++r) op[(size_t)r * LL] = acc[oi][ni][r];
    }
  }
  // BN partials: sum / sum-of-squares over this block's 128 l per o
#pragma unroll
  for (int oi = 0; oi < 2; ++oi) {
#pragma unroll
    for (int r = 0; r < 4; ++r) {
      float ps = 0.f, ps2 = 0.f;
#pragma unroll
      for (int ni = 0; ni < 4; ++ni) {
        float v = acc[oi][ni][r];
        ps += v;
        ps2 += v * v;
      }
      ps  += __shfl_xor(ps, 1);  ps  += __shfl_xor(ps, 2);
      ps  += __shfl_xor(ps, 4);  ps  += __shfl_xor(ps, 8);
      ps2 += __shfl_xor(ps2, 1); ps2 += __shfl_xor(ps2, 2);
      ps2 += __shfl_xor(ps2, 4); ps2 += __shfl_xor(ps2, 8);
      if (llo == 0) {
        int ol = wo * 32 + oi * 16 + lhi * 4 + r;
        atomicAdd(&bnl_s[ol], ps);
        atomicAdd(&bnl_s2[ol], ps2);
      }
    }
  }
  __syncthreads();
  if (t < 128) {
    size_t slot = ((size_t)(lblk * 32 + b) * 5 + ob) * 128 + t;
    bnp_s[slot]  = bnl_s[t];
    bnp_s2[slot] = bnl_s2[t];
  }
}

// ---------------------------------------------------------------------------
// BN finalize: reduce 1024 partials per channel -> scale a, shift b
// ---------------------------------------------------------------------------
__launch_bounds__(256)
__global__ void bn_finalize(const float* __restrict__ bnp_s,
                            const float* __restrict__ bnp_s2,
                            const float* __restrict__ gamma,
                            const float* __restrict__ beta,
                            float* __restrict__ ab) {
  const int o = blockIdx.x;
  const int t = threadIdx.x;
  const int ot = o >> 7, oc = o & 127;
  float s = 0.f, s2 = 0.f;
  for (int lb = t; lb < 1024; lb += 256) {
    size_t idx = ((size_t)lb * 5 + ot) * 128 + oc;
    s  += bnp_s[idx];
    s2 += bnp_s2[idx];
  }
#pragma unroll
  for (int m = 1; m < 64; m <<= 1) {
    s  += __shfl_xor(s, m);
    s2 += __shfl_xor(s2, m);
  }
  __shared__ float red[8];
  int lane = t & 63, w = t >> 6;
  if (lane == 0) { red[w] = s; red[4 + w] = s2; }
  __syncthreads();
  if (t == 0) {
    float S  = red[0] + red[1] + red[2] + red[3];
    float S2 = red[4] + red[5] + red[6] + red[7];
    float mean = S * (1.0f / 131072.0f);
    float var  = S2 * (1.0f / 131072.0f) - mean * mean;
    float a = gamma[o] * rsqrtf(var + 1e-5f);
    ab[o]       = a;
    ab[640 + o] = beta[o] - mean * a;
  }
}

__launch_bounds__(256)
__global__ void bn_apply(float* __restrict__ out, const float* __restrict__ ab) {
  size_t i4 = (size_t)blockIdx.x * 256 + threadIdx.x;
  if (i4 >= 20971520ull) return;
  int o = (int)((i4 >> 10) % 640);
  float a = ab[o], bs = ab[640 + o];
  float4 v = ((const float4*)out)[i4];
  v.x = fmaxf(fmaf(v.x, a, bs), 0.f);
  v.y = fmaxf(fmaf(v.y, a, bs), 0.f);
  v.z = fmaxf(fmaf(v.z, a, bs), 0.f);
  v.w = fmaxf(fmaf(v.w, a, bs), 0.f);
  ((float4*)out)[i4] = v;
}

// ---------------------------------------------------------------------------
extern "C" void kernel_launch(void* const* d_in, const int* in_sizes, int n_in,
                              void* d_out, int out_size, void* d_ws,
                              size_t ws_size, hipStream_t stream) {
  (void)in_sizes; (void)n_in; (void)out_size; (void)ws_size;
  const float* x     = (const float*)d_in[0];
  const float* w0    = (const float*)d_in[1];
  const float* w1    = (const float*)d_in[2];
  const float* w2    = (const float*)d_in[3];
  const float* w3    = (const float*)d_in[4];
  const float* wmp   = (const float*)d_in[5];
  const float* qkvw  = (const float*)d_in[6];
  const float* qkvb  = (const float*)d_in[7];
  const float* sew1  = (const float*)d_in[8];
  const float* sew2  = (const float*)d_in[9];
  const float* wbott = (const float*)d_in[10];
  const float* gamma = (const float*)d_in[11];
  const float* beta  = (const float*)d_in[12];
  float* out = (float*)d_out;

  // Workspace layout (bytes):
  //   Ft2 (bf16 [b][kg=80][l][8])  : 167,772,160
  //   union { Xt bf16 [b][l][128] (33,554,432) ; Weff bf16 (26,214,400) }
  //     (Xt consumed by convs before make_weff writes Weff)
  //   wtb bf16                     : 1,146,880
  //   f32 tail: gsum/attg/sg/ab/bnp_s/bnp_s2
  char* ws = (char*)d_ws;
  unsigned short* Ft   = (unsigned short*)ws;
  unsigned short* XtW  = (unsigned short*)(ws + 167772160u);
  unsigned short* Xt   = XtW;
  unsigned short* Weff = XtW;
  unsigned short* wtb  = (unsigned short*)(ws + 167772160u + 33554432u);
  float* f32a  = (float*)(ws + 167772160u + 33554432u + 1146880u);
  float* gsum  = f32a;              // 20480
  float* attg  = gsum + 20480;      // 800
  float* sg    = attg + 800;        // 20480
  float* ab    = sg + 20480;        // 1280
  float* bnp_s  = ab + 1280;        // 655360
  float* bnp_s2 = bnp_s + 655360;   // 655360

  hipMemsetAsync(gsum, 0, 20480 * sizeof(float), stream);

  wtransb<<<(311296 + 255) / 256, 256, 0, stream>>>(w0,  wtb,          19, 311296);
  wtransb<<<(147456 + 255) / 256, 256, 0, stream>>>(w1,  wtb + 311296,  9, 147456);
  wtransb<<< (81920 + 255) / 256, 256, 0, stream>>>(w2,  wtb + 458752,  5,  81920);
  wtransb<<< (16384 + 255) / 256, 256, 0, stream>>>(w3,  wtb + 540672,  1,  16384);
  wtransb<<< (16384 + 255) / 256, 256, 0, stream>>>(wmp, wtb + 557056,  1,  16384);

  prep_xt<<<dim3(64, 32), 256, 0, stream>>>(x, Xt);

  conv_all<<<dim3(64, 32, 2), 256, 0, stream>>>(Xt, wtb, Ft, gsum);

  attn_se<<<32, 128, 0, stream>>>(gsum, qkvw, qkvb, sew1, sew2, attg, sg);
  make_weff<<<dim3(1600, 32), 256, 0, stream>>>(wbott, attg, sg, Weff);
  gemm_bott_mfma<<<dim3(5, 32, 32), 512, 0, stream>>>(Weff, Ft, out, bnp_s,
                                                      bnp_s2);
  bn_finalize<<<640, 256, 0, stream>>>(bnp_s, bnp_s2, gamma, beta, ab);
  bn_apply<<<81920, 256, 0, stream>>>(out, ab);
}

// Round 10
// 966.623 us; speedup vs baseline: 1.1303x; 1.1303x over previous
//
#include <hip/hip_runtime.h>
#include <math.h>

// Problem constants
#define LL 4096
#define BATCH 32
#define NIC 128
#define NFC 128

typedef __attribute__((ext_vector_type(8))) short short8;
typedef __attribute__((ext_vector_type(4))) float floatx4;

__device__ __forceinline__ unsigned short f2bf(float f) {
  unsigned u = __builtin_bit_cast(unsigned, f);
  u += 0x7fffu + ((u >> 16) & 1u);  // round-to-nearest-even
  return (unsigned short)(u >> 16);
}
__device__ __forceinline__ float bf2f(unsigned short h) {
  unsigned u = ((unsigned)h) << 16;
  return __builtin_bit_cast(float, u);
}

// ---------------------------------------------------------------------------
// Weight prep: src fp32 [O=128][I=128][K] -> dst bf16 [k][cig(16)][o(128)][8]
// where ci = cig*8 + e.  MFMA A-fragment load for (o, kc, lhi) is then
// 16 llo-lanes x 16 B CONTIGUOUS (256-B segments) -> coalesced L2 reads.
// ---------------------------------------------------------------------------
__global__ void wtransb(const float* __restrict__ src,
                        unsigned short* __restrict__ dst, int K, int n) {
  int f = blockIdx.x * 256 + threadIdx.x;
  if (f >= n) return;
  int o   = f / (128 * K);
  int rem = f - o * 128 * K;
  int ci  = rem / K;
  int k   = rem - ci * K;
  dst[((k * 16 + (ci >> 3)) * 128 + o) * 8 + (ci & 7)] = f2bf(src[f]);
}

// ---------------------------------------------------------------------------
// Prepass: x fp32 [b][ci][l] -> Xt bf16 [b][l][ci]  (LDS tile transpose)
// ---------------------------------------------------------------------------
__launch_bounds__(256)
__global__ void prep_xt(const float* __restrict__ x,
                        unsigned short* __restrict__ xt) {
  __shared__ unsigned short tb[64 * 136];
  const int b  = blockIdx.y;
  const int l0 = blockIdx.x * 64;
  const int t  = threadIdx.x;
  for (int idx = t; idx < 2048; idx += 256) {
    int ci = idx >> 4;
    int l4 = (idx & 15) * 4;
    float4 v = *(const float4*)&x[((size_t)b * 128 + ci) * LL + l0 + l4];
    tb[(l4 + 0) * 136 + ci] = f2bf(v.x);
    tb[(l4 + 1) * 136 + ci] = f2bf(v.y);
    tb[(l4 + 2) * 136 + ci] = f2bf(v.z);
    tb[(l4 + 3) * 136 + ci] = f2bf(v.w);
  }
  __syncthreads();
  for (int idx = t; idx < 1024; idx += 256) {
    int l  = idx >> 4;
    int cg = (idx & 15) * 8;
    *(short8*)&xt[((size_t)b * LL + l0 + l) * 128 + cg] =
        *(const short8*)&tb[l * 136 + cg];
  }
}

// ---------------------------------------------------------------------------
// FUSED conv branches via bf16 MFMA — role-split for occupancy (R5 version,
// l-major Ft epilogue restored: the R7 k-major epilogue cost conv ~60 us).
//   role 0: branch 0 only  (K=19, halo 9, 82 staged rows, 19 taps)
//   role 1: branches 1..4  (halo 4, 72 staged rows, 16 taps + maxpool)
// ---------------------------------------------------------------------------
__launch_bounds__(256)
__global__ void conv_all(const unsigned short* __restrict__ xt,
                         const unsigned short* __restrict__ wtb,
                         unsigned short* __restrict__ Ft,
                         float* __restrict__ gsum) {
  __shared__ unsigned short Bs[82 * 136];
  const int role = blockIdx.z;
  const int halo = role ? 4 : 9;
  const int rows = role ? 72 : 82;
  const int b  = blockIdx.y;
  const int l0 = blockIdx.x * 64;
  const int t  = threadIdx.x;
  const int lane = t & 63;
  const int wo   = t >> 6;  // wave id = o-group (32 o each)
  const int lhi = lane >> 4;
  const int llo = lane & 15;
  const unsigned short* xb = xt + (size_t)b * LL * 128;

  // ---- stage x tile once (bf16), halo zero-padded ----
  for (int idx = t; idx < rows * 16; idx += 256) {
    int r  = idx >> 4;
    int cg = (idx & 15) * 8;
    int l  = l0 - halo + r;
    short8 v = {0, 0, 0, 0, 0, 0, 0, 0};
    if (l >= 0 && l < LL) v = *(const short8*)&xb[(size_t)l * 128 + cg];
    *(short8*)&Bs[r * 136 + cg] = v;
  }
  __syncthreads();

  const int brlo = role ? 1 : 0;
  const int brhi = role ? 5 : 1;
#pragma clang loop unroll(disable)
  for (int br = brlo; br < brhi; ++br) {
    if (br == 4) {
      // ---- in-LDS maxpool3 of central 64 rows (rows halo..halo+63) ----
      short8 pv[4];
#pragma unroll
      for (int i = 0; i < 4; ++i) {
        int idx = t + i * 256;
        int r  = idx >> 4;
        int cg = (idx & 15) * 8;
        int l  = l0 + r;
        float m[8];
#pragma unroll
        for (int e = 0; e < 8; ++e) m[e] = -INFINITY;
#pragma unroll
        for (int d = 0; d < 3; ++d) {
          int ls = l - 1 + d;
          if (ls >= 0 && ls < LL) {
            short8 v = *(const short8*)&Bs[(r + halo - 1 + d) * 136 + cg];
#pragma unroll
            for (int e = 0; e < 8; ++e)
              m[e] = fmaxf(m[e], bf2f((unsigned short)v[e]));
          }
        }
#pragma unroll
        for (int e = 0; e < 8; ++e) pv[i][e] = (short)f2bf(m[e]);
      }
      __syncthreads();
#pragma unroll
      for (int i = 0; i < 4; ++i) {
        int idx = t + i * 256;
        int r  = idx >> 4;
        int cg = (idx & 15) * 8;
        *(short8*)&Bs[(r + halo) * 136 + cg] = pv[i];
      }
      __syncthreads();
    }

    int K, wof;
    switch (br) {
      case 0:  K = 19; wof = 0;      break;
      case 1:  K = 9;  wof = 311296; break;
      case 2:  K = 5;  wof = 458752; break;
      case 3:  K = 1;  wof = 540672; break;
      default: K = 1;  wof = 557056; break;
    }
    const int roff = halo - K / 2;

    floatx4 acc[2][4];
#pragma unroll
    for (int oi = 0; oi < 2; ++oi)
#pragma unroll
      for (int ni = 0; ni < 4; ++ni) acc[oi][ni] = (floatx4)0.0f;

    for (int tap = 0; tap < K; ++tap) {
      const unsigned short* wb = wtb + wof + tap * 16384;
#pragma unroll
      for (int kc = 0; kc < 4; ++kc) {
        short8 af[2], bfr[4];
#pragma unroll
        for (int oi = 0; oi < 2; ++oi) {
          int o = wo * 32 + oi * 16 + llo;
          af[oi] = *(const short8*)&wb[((kc * 4 + lhi) * 128 + o) * 8];
        }
#pragma unroll
        for (int ni = 0; ni < 4; ++ni) {
          int row = ni * 16 + llo + tap + roff;
          bfr[ni] = *(const short8*)&Bs[row * 136 + kc * 32 + lhi * 8];
        }
#pragma unroll
        for (int oi = 0; oi < 2; ++oi)
#pragma unroll
          for (int ni = 0; ni < 4; ++ni)
            acc[oi][ni] = __builtin_amdgcn_mfma_f32_16x16x32_bf16(
                af[oi], bfr[ni], acc[oi][ni], 0, 0, 0);
      }
    }

    // ---- epilogue: Ft (l-major bf16) + GAP partial sums ----
#pragma unroll
    for (int oi = 0; oi < 2; ++oi) {
#pragma unroll
      for (int ni = 0; ni < 4; ++ni) {
        int ob = wo * 32 + oi * 16 + lhi * 4;
        int l  = l0 + ni * 16 + llo;
        unsigned short tmp[4];
#pragma unroll
        for (int r = 0; r < 4; ++r) tmp[r] = f2bf(acc[oi][ni][r]);
        *(uint2*)&Ft[((size_t)b * LL + l) * 640 + br * NFC + ob] =
            *(uint2*)tmp;
      }
    }
#pragma unroll
    for (int oi = 0; oi < 2; ++oi) {
#pragma unroll
      for (int r = 0; r < 4; ++r) {
        float ps =
            acc[oi][0][r] + acc[oi][1][r] + acc[oi][2][r] + acc[oi][3][r];
        ps += __shfl_xor(ps, 1);
        ps += __shfl_xor(ps, 2);
        ps += __shfl_xor(ps, 4);
        ps += __shfl_xor(ps, 8);
        if (llo == 0)
          atomicAdd(&gsum[((size_t)br * BATCH + b) * NFC + wo * 32 + oi * 16 +
                          lhi * 4 + r],
                    ps);
      }
    }
  }
}

// ---------------------------------------------------------------------------
// Attention + SE head (unchanged)
// ---------------------------------------------------------------------------
__launch_bounds__(128)
__global__ void attn_se(const float* __restrict__ gsum,
                        const float* __restrict__ qkvw,
                        const float* __restrict__ qkvb,
                        const float* __restrict__ sew1,
                        const float* __restrict__ sew2,
                        float* __restrict__ attg, float* __restrict__ sg) {
  __shared__ float gap[640];
  __shared__ float qkvv[1920];
  __shared__ float en[100];
  __shared__ float att[25];
  __shared__ float h1[40];
  __shared__ float yv[640];
  const int b = blockIdx.x;
  const int t = threadIdx.x;

  for (int i = t; i < 640; i += 128) {
    int jj = i >> 7, c = i & 127;
    gap[i] = gsum[((size_t)jj * BATCH + b) * NFC + c] * (1.0f / 4096.0f);
  }
  __syncthreads();
  for (int rr = t; rr < 1920; rr += 128) {
    int i = rr / 384, r = rr - i * 384;
    const float* wr = qkvw + (size_t)r * 128;
    float a = qkvb[r];
    for (int c = 0; c < 128; ++c) a = fmaf(wr[c], gap[i * 128 + c], a);
    qkvv[i * 384 + r] = a;
  }
  __syncthreads();
  if (t < 100) {
    int h = t / 25, rem = t - h * 25, i = rem / 5, i2 = rem - i * 5;
    float e = 0.f;
    for (int d = 0; d < 32; ++d)
      e = fmaf(qkvv[i * 384 + h * 96 + d * 3],
               qkvv[i2 * 384 + h * 96 + d * 3 + 1], e);
    en[t] = e * 0.08838834764831845f;
  }
  __syncthreads();
  if (t < 20) {
    float* row = &en[t * 5];
    float mx = row[0];
    for (int k = 1; k < 5; ++k) mx = fmaxf(mx, row[k]);
    float ex[5];
    float sm = 0.f;
    for (int k = 0; k < 5; ++k) { ex[k] = expf(row[k] - mx); sm += ex[k]; }
    float inv = 1.0f / sm;
    for (int k = 0; k < 5; ++k) row[k] = ex[k] * inv;
  }
  __syncthreads();
  if (t < 25) {
    float a = 0.25f * (en[t] + en[25 + t] + en[50 + t] + en[75 + t]);
    att[t] = a;
    attg[b * 25 + t] = a;
  }
  __syncthreads();
  for (int i = t; i < 640; i += 128) {
    int ii = i >> 7, c = i & 127;
    float a = 0.f;
    for (int jj = 0; jj < 5; ++jj)
      a = fmaf(att[ii * 5 + jj], gap[jj * 128 + c], a);
    yv[i] = a;
  }
  __syncthreads();
  if (t < 40) {
    const float* wr = sew1 + (size_t)t * 640;
    float a = 0.f;
    for (int c = 0; c < 640; ++c) a = fmaf(wr[c], yv[c], a);
    h1[t] = fmaxf(a, 0.f);
  }
  __syncthreads();
  for (int i = t; i < 640; i += 128) {
    const float* wr = sew2 + (size_t)i * 40;
    float a = 0.f;
    for (int r = 0; r < 40; ++r) a = fmaf(wr[r], h1[r], a);
    sg[(size_t)b * 640 + i] = 1.0f / (1.0f + expf(-a));
  }
}

// ---------------------------------------------------------------------------
// Weff[b][kg][o][8] (kg=k>>3) = sum_i att[b,i,j]*s[b,k]*w_bott[o,k]  (bf16)
// ---------------------------------------------------------------------------
__launch_bounds__(256)
__global__ void make_weff(const float* __restrict__ wbott,
                          const float* __restrict__ attg,
                          const float* __restrict__ sg,
                          unsigned short* __restrict__ weff) {
  __shared__ float att[25];
  __shared__ float s[640];
  const int b = blockIdx.y;
  const int t = threadIdx.x;
  if (t < 25) att[t] = attg[b * 25 + t];
  for (int i = t; i < 640; i += 256) s[i] = sg[(size_t)b * 640 + i];
  __syncthreads();
  const int f  = blockIdx.x * 256 + t;
  const int o  = f / 640;
  const int jc = f - o * 640;
  const int jj = jc >> 7, c = jc & 127;
  float a = 0.f;
#pragma unroll
  for (int i = 0; i < 5; ++i)
    a = fmaf(att[i * 5 + jj] * s[i * 128 + c],
             wbott[(size_t)o * 640 + i * 128 + c], a);
  weff[(size_t)b * 409600 + (((size_t)(jc >> 3) * 640 + o) << 3) + (jc & 7)] =
      f2bf(a);
}

// ---------------------------------------------------------------------------
// Bottleneck GEMM v5 = v3 structure (LDS multicast kept — v4's L2-direct B
// regressed by multiplying L2 traffic) with two targeted changes:
//   (1) K_STEP 64 -> 128: 5 k-steps, HALF the barrier-drain points; the
//       B-prefetch regs are issued before the 32-MFMA phase and committed
//       after it (~1500 cyc in flight).
//   (2) T2 XOR swizzle on the B tile (chunk ^= row&7, write AND read side):
//       kills the 8-way conflict of the old stride-72 layout (1.31e7
//       conflict-cycles ~ 21 us/dispatch).
// Stride 132 shorts; LDS 2x128x132x2 = 67.6 KB -> still 2 blocks/CU.
// ---------------------------------------------------------------------------
__launch_bounds__(512, 4)
__global__ void gemm_bott_mfma(const unsigned short* __restrict__ weff,
                               const unsigned short* __restrict__ Ft,
                               float* __restrict__ out,
                               float* __restrict__ bnp_s,
                               float* __restrict__ bnp_s2) {
  __shared__ unsigned short Bs[2][128 * 132];
  __shared__ float bnl_s[128];
  __shared__ float bnl_s2[128];
  const int g = blockIdx.x + 5 * (blockIdx.y + 32 * blockIdx.z);
  const int wrk = (g & 7) * 640 + (g >> 3);  // bijective: 5120 = 8 * 640
  const int ob   = wrk % 5;
  const int ybz  = wrk / 5;
  const int lblk = ybz & 31;
  const int b    = ybz >> 5;
  const int o0 = ob * 128;
  const int l0 = lblk * 128;
  const int t    = threadIdx.x;
  const int lane = t & 63;
  const int wid  = t >> 6;
  const int wo = wid & 3, wl = wid >> 2;
  const int lhi = lane >> 4;
  const int llo = lane & 15;
  const unsigned short* wb = weff + (size_t)b * 409600;
  const unsigned short* fb = Ft + (size_t)b * (size_t)LL * 640;
  if (t < 128) { bnl_s[t] = 0.f; bnl_s2[t] = 0.f; }

  // staging geometry: thread covers 4 rows (tr+32i), one 16-B chunk each
  const int tr   = t >> 4;        // 0..31
  const int tc8  = t & 15;        // logical chunk 0..15
  const int tcol = tc8 * 8;
  const int cw   = (tc8 ^ (tr & 7)) * 8;  // swizzled slot (row&7 == tr&7)

  // prologue: stage k-step 0 into buf 0
#pragma unroll
  for (int i = 0; i < 4; ++i) {
    int row = tr + 32 * i;
    short8 v = *(const short8*)&fb[(size_t)(l0 + row) * 640 + tcol];
    *(short8*)&Bs[0][row * 132 + cw] = v;
  }
  __syncthreads();

  floatx4 acc[2][4];
#pragma unroll
  for (int oi = 0; oi < 2; ++oi)
#pragma unroll
    for (int ni = 0; ni < 4; ++ni) acc[oi][ni] = (floatx4)0.0f;

  int cur = 0;
  for (int p = 0; p < 5; ++p) {
    // issue next-tile loads (in flight across this step's 32 MFMAs)
    short8 r0, r1, r2, r3;
    if (p < 4) {
      const size_t kb = (size_t)(p + 1) * 128 + tcol;
      r0 = *(const short8*)&fb[(size_t)(l0 + tr) * 640 + kb];
      r1 = *(const short8*)&fb[(size_t)(l0 + tr + 32) * 640 + kb];
      r2 = *(const short8*)&fb[(size_t)(l0 + tr + 64) * 640 + kb];
      r3 = *(const short8*)&fb[(size_t)(l0 + tr + 96) * 640 + kb];
    }
#pragma unroll
    for (int s = 0; s < 4; ++s) {
      short8 af[2], bf[4];
#pragma unroll
      for (int oi = 0; oi < 2; ++oi) {
        int o = o0 + wo * 32 + oi * 16 + llo;
        af[oi] = *(const short8*)
            &wb[(((size_t)(p * 16 + s * 4 + lhi)) * 640 + o) * 8];
      }
#pragma unroll
      for (int ni = 0; ni < 4; ++ni) {
        int n = wl * 64 + ni * 16 + llo;
        bf[ni] = *(const short8*)
            &Bs[cur][n * 132 + (((s * 4 + lhi) ^ (n & 7)) * 8)];
      }
#pragma unroll
      for (int oi = 0; oi < 2; ++oi)
#pragma unroll
        for (int ni = 0; ni < 4; ++ni)
          acc[oi][ni] = __builtin_amdgcn_mfma_f32_16x16x32_bf16(
              af[oi], bf[ni], acc[oi][ni], 0, 0, 0);
    }
    if (p < 4) {
      *(short8*)&Bs[cur ^ 1][tr * 132 + cw] = r0;
      *(short8*)&Bs[cur ^ 1][(tr + 32) * 132 + cw] = r1;
      *(short8*)&Bs[cur ^ 1][(tr + 64) * 132 + cw] = r2;
      *(short8*)&Bs[cur ^ 1][(tr + 96) * 132 + cw] = r3;
    }
    __syncthreads();
    cur ^= 1;
  }

#pragma unroll
  for (int oi = 0; oi < 2; ++oi) {
#pragma unroll
    for (int ni = 0; ni < 4; ++ni) {
      int o = o0 + wo * 32 + oi * 16 + lhi * 4;
      int l = l0 + wl * 64 + ni * 16 + llo;
      float* op = out + ((size_t)b * 640 + o) * LL + l;
#pragma unroll
      for (int r = 0; r < 4; ++r) op[(size_t)r * LL] = acc[oi][ni][r];
    }
  }
  // BN partials: sum / sum-of-squares over this block's 128 l per o
#pragma unroll
  for (int oi = 0; oi < 2; ++oi) {
#pragma unroll
    for (int r = 0; r < 4; ++r) {
      float ps = 0.f, ps2 = 0.f;
#pragma unroll
      for (int ni = 0; ni < 4; ++ni) {
        float v = acc[oi][ni][r];
        ps += v;
        ps2 += v * v;
      }
      ps  += __shfl_xor(ps, 1);  ps  += __shfl_xor(ps, 2);
      ps  += __shfl_xor(ps, 4);  ps  += __shfl_xor(ps, 8);
      ps2 += __shfl_xor(ps2, 1); ps2 += __shfl_xor(ps2, 2);
      ps2 += __shfl_xor(ps2, 4); ps2 += __shfl_xor(ps2, 8);
      if (llo == 0) {
        int ol = wo * 32 + oi * 16 + lhi * 4 + r;
        atomicAdd(&bnl_s[ol], ps);
        atomicAdd(&bnl_s2[ol], ps2);
      }
    }
  }
  __syncthreads();
  if (t < 128) {
    size_t slot = ((size_t)(lblk * 32 + b) * 5 + ob) * 128 + t;
    bnp_s[slot]  = bnl_s[t];
    bnp_s2[slot] = bnl_s2[t];
  }
}

// ---------------------------------------------------------------------------
// BN finalize: reduce 1024 partials per channel -> scale a, shift b
// ---------------------------------------------------------------------------
__launch_bounds__(256)
__global__ void bn_finalize(const float* __restrict__ bnp_s,
                            const float* __restrict__ bnp_s2,
                            const float* __restrict__ gamma,
                            const float* __restrict__ beta,
                            float* __restrict__ ab) {
  const int o = blockIdx.x;
  const int t = threadIdx.x;
  const int ot = o >> 7, oc = o & 127;
  float s = 0.f, s2 = 0.f;
  for (int lb = t; lb < 1024; lb += 256) {
    size_t idx = ((size_t)lb * 5 + ot) * 128 + oc;
    s  += bnp_s[idx];
    s2 += bnp_s2[idx];
  }
#pragma unroll
  for (int m = 1; m < 64; m <<= 1) {
    s  += __shfl_xor(s, m);
    s2 += __shfl_xor(s2, m);
  }
  __shared__ float red[8];
  int lane = t & 63, w = t >> 6;
  if (lane == 0) { red[w] = s; red[4 + w] = s2; }
  __syncthreads();
  if (t == 0) {
    float S  = red[0] + red[1] + red[2] + red[3];
    float S2 = red[4] + red[5] + red[6] + red[7];
    float mean = S * (1.0f / 131072.0f);
    float var  = S2 * (1.0f / 131072.0f) - mean * mean;
    float a = gamma[o] * rsqrtf(var + 1e-5f);
    ab[o]       = a;
    ab[640 + o] = beta[o] - mean * a;
  }
}

__launch_bounds__(256)
__global__ void bn_apply(float* __restrict__ out, const float* __restrict__ ab) {
  size_t i4 = (size_t)blockIdx.x * 256 + threadIdx.x;
  if (i4 >= 20971520ull) return;
  int o = (int)((i4 >> 10) % 640);
  float a = ab[o], bs = ab[640 + o];
  float4 v = ((const float4*)out)[i4];
  v.x = fmaxf(fmaf(v.x, a, bs), 0.f);
  v.y = fmaxf(fmaf(v.y, a, bs), 0.f);
  v.z = fmaxf(fmaf(v.z, a, bs), 0.f);
  v.w = fmaxf(fmaf(v.w, a, bs), 0.f);
  ((float4*)out)[i4] = v;
}

// ---------------------------------------------------------------------------
extern "C" void kernel_launch(void* const* d_in, const int* in_sizes, int n_in,
                              void* d_out, int out_size, void* d_ws,
                              size_t ws_size, hipStream_t stream) {
  (void)in_sizes; (void)n_in; (void)out_size; (void)ws_size;
  const float* x     = (const float*)d_in[0];
  const float* w0    = (const float*)d_in[1];
  const float* w1    = (const float*)d_in[2];
  const float* w2    = (const float*)d_in[3];
  const float* w3    = (const float*)d_in[4];
  const float* wmp   = (const float*)d_in[5];
  const float* qkvw  = (const float*)d_in[6];
  const float* qkvb  = (const float*)d_in[7];
  const float* sew1  = (const float*)d_in[8];
  const float* sew2  = (const float*)d_in[9];
  const float* wbott = (const float*)d_in[10];
  const float* gamma = (const float*)d_in[11];
  const float* beta  = (const float*)d_in[12];
  float* out = (float*)d_out;

  // Workspace layout (bytes):
  //   Ft (bf16 [b][l][640])        : 167,772,160
  //   union { Xt bf16 [b][l][128] (33,554,432) ; Weff bf16 (26,214,400) }
  //     (Xt consumed by convs before make_weff writes Weff)
  //   wtb bf16                     : 1,146,880
  //   f32 tail: gsum/attg/sg/ab/bnp_s/bnp_s2
  char* ws = (char*)d_ws;
  unsigned short* Ft   = (unsigned short*)ws;
  unsigned short* XtW  = (unsigned short*)(ws + 167772160u);
  unsigned short* Xt   = XtW;
  unsigned short* Weff = XtW;
  unsigned short* wtb  = (unsigned short*)(ws + 167772160u + 33554432u);
  float* f32a  = (float*)(ws + 167772160u + 33554432u + 1146880u);
  float* gsum  = f32a;              // 20480
  float* attg  = gsum + 20480;      // 800
  float* sg    = attg + 800;        // 20480
  float* ab    = sg + 20480;        // 1280
  float* bnp_s  = ab + 1280;        // 655360
  float* bnp_s2 = bnp_s + 655360;   // 655360

  hipMemsetAsync(gsum, 0, 20480 * sizeof(float), stream);

  wtransb<<<(311296 + 255) / 256, 256, 0, stream>>>(w0,  wtb,          19, 311296);
  wtransb<<<(147456 + 255) / 256, 256, 0, stream>>>(w1,  wtb + 311296,  9, 147456);
  wtransb<<< (81920 + 255) / 256, 256, 0, stream>>>(w2,  wtb + 458752,  5,  81920);
  wtransb<<< (16384 + 255) / 256, 256, 0, stream>>>(w3,  wtb + 540672,  1,  16384);
  wtransb<<< (16384 + 255) / 256, 256, 0, stream>>>(wmp, wtb + 557056,  1,  16384);

  prep_xt<<<dim3(64, 32), 256, 0, stream>>>(x, Xt);

  conv_all<<<dim3(64, 32, 2), 256, 0, stream>>>(Xt, wtb, Ft, gsum);

  attn_se<<<32, 128, 0, stream>>>(gsum, qkvw, qkvb, sew1, sew2, attg, sg);
  make_weff<<<dim3(1600, 32), 256, 0, stream>>>(wbott, attg, sg, Weff);
  gemm_bott_mfma<<<dim3(5, 32, 32), 512, 0, stream>>>(Weff, Ft, out, bnp_s,
                                                      bnp_s2);
  bn_finalize<<<640, 256, 0, stream>>>(bnp_s, bnp_s2, gamma, beta, ab);
  bn_apply<<<81920, 256, 0, stream>>>(out, ab);
}